// Round 2
// 2646.614 us; speedup vs baseline: 1.1119x; 1.1119x over previous
//
#include <hip/hip_runtime.h>
#include <hip/hip_bf16.h>
#include <math.h>

typedef __bf16 bf16;
typedef __bf16 bf16x8 __attribute__((ext_vector_type(8)));
typedef __bf16 bf16x4 __attribute__((ext_vector_type(4)));
typedef float  f32x4  __attribute__((ext_vector_type(4)));

#define B_  4
#define N_  1024
#define C_  768
#define H_  12
#define HD_ 64
#define FF_ 3072
#define T_  (B_*N_)      // 4096 tokens
#define D_  12

// ---- async global->LDS, 16B per lane, wave-uniform LDS base ----
__device__ __forceinline__ void gld_lds16(const void* g, void* l) {
    __builtin_amdgcn_global_load_lds(
        (const __attribute__((address_space(1))) void*)g,
        (__attribute__((address_space(3))) void*)l, 16, 0, 0);
}

// =====================================================================
// GEMM:  out[M,N] = A[M,K] @ Bt[N,K]^T + bias
//   A: bf16 activations. WT = bf16 (preconverted weights) or float
//   (fallback: swizzled fp32 staging + in-loop cvt).
// MODE 0: store bf16   MODE 1: GELU(exact) then store bf16
// MODE 2: resid[M,N] (fp32) atomicAdd (split-K safe; bias only on z==0)
// 128x128 tile, BK=64 (halved barrier drains vs BK=32), 4 waves 2x2,
// each wave 64x64 via 4x4 16x16x32 MFMA, two K=32 sub-steps per stage.
// LDS XOR-swizzle (chunk ^ row&7) both-sides: pre-swizzled GLOBAL source,
// linear LDS dest (global_load_lds constraint), swizzled ds_read -> the
// fragment read is bank-conflict-free (was 8-way at BK=32 linear).
// =====================================================================
template<typename WT, int MODE>
__global__ __launch_bounds__(256) void gemm_bt(
    const bf16* __restrict__ A, const WT* __restrict__ Bt,
    const float* __restrict__ bias, bf16* __restrict__ out,
    float* __restrict__ resid, int M, int N, int Kfull, int Ks)
{
    __shared__ __align__(16) bf16 lA[128*64];   // 16 KB  [row][64k] swizzled
    __shared__ __align__(16) WT   lB[128*64];   // 16 KB bf16 / 32 KB f32
    const int tid  = threadIdx.x;
    const int lane = tid & 63, wave = tid >> 6;
    const int lo = lane & 15, hi = lane >> 4;
    const int wm = wave & 1, wn = wave >> 1;
    const int row0 = blockIdx.x * 128, col0 = blockIdx.y * 128;
    const int k0base = blockIdx.z * Ks;

    f32x4 acc[4][4];
#pragma unroll
    for (int i = 0; i < 4; i++)
#pragma unroll
        for (int j = 0; j < 4; j++) acc[i][j] = (f32x4){0.f, 0.f, 0.f, 0.f};

    for (int k0 = k0base; k0 < k0base + Ks; k0 += 64) {
        // A tile: 1024 chunks x 16B (8 bf16), LDS linear [row][8 chunks],
        // global source chunk = kc ^ (row&7)
#pragma unroll
        for (int r = 0; r < 4; ++r) {
            const int cb    = r * 256 + wave * 64;   // wave-uniform base
            const int chunk = cb + lane;
            const int rw = chunk >> 3, kc = chunk & 7;
            const int kcs = kc ^ (rw & 7);
            gld_lds16(A + (size_t)(row0 + rw) * Kfull + k0 + kcs * 8, lA + cb * 8);
        }
        if constexpr (sizeof(WT) == 2) {
#pragma unroll
            for (int r = 0; r < 4; ++r) {
                const int cb    = r * 256 + wave * 64;
                const int chunk = cb + lane;
                const int rw = chunk >> 3, kc = chunk & 7;
                const int kcs = kc ^ (rw & 7);
                gld_lds16(Bt + (size_t)(col0 + rw) * Kfull + k0 + kcs * 8,
                          (bf16*)lB + cb * 8);
            }
        } else {
            // B tile fp32: 2048 chunks x 16B, swizzle kc ^ ((row&7)<<1)
#pragma unroll
            for (int r = 0; r < 8; ++r) {
                const int cb    = r * 256 + wave * 64;
                const int chunk = cb + lane;
                const int rw = chunk >> 4, kc = chunk & 15;
                const int kcs = kc ^ ((rw & 7) << 1);
                gld_lds16(Bt + (size_t)(col0 + rw) * Kfull + k0 + kcs * 4,
                          (float*)lB + cb * 4);
            }
        }
        __syncthreads();
        // two K=32 sub-steps; NOT unrolled so fragment liveness stays at
        // the m97 level (~164 VGPR, 3 waves/SIMD) — avoid m132 cliff
#pragma unroll 1
        for (int s = 0; s < 2; ++s) {
            bf16x8 af[4], bfr[4];
#pragma unroll
            for (int i = 0; i < 4; i++) {
                const int rowA = wm * 64 + i * 16 + lo;
                const int ca = (s * 4 + hi) ^ (lo & 7);
                af[i] = *(const bf16x8*)(lA + rowA * 64 + ca * 8);
            }
#pragma unroll
            for (int i = 0; i < 4; i++) {
                const int rowB = wn * 64 + i * 16 + lo;
                if constexpr (sizeof(WT) == 2) {
                    const int cb = (s * 4 + hi) ^ (lo & 7);
                    bfr[i] = *(const bf16x8*)((const bf16*)lB + rowB * 64 + cb * 8);
                } else {
                    const float* base = (const float*)lB + rowB * 64;
                    const int c0 = (s * 8 + hi * 2) ^ ((lo & 7) << 1);
                    const f32x4 u0 = *(const f32x4*)(base + c0 * 4);
                    const f32x4 u1 = *(const f32x4*)(base + (c0 + 1) * 4);
                    bf16x8 f;
#pragma unroll
                    for (int e = 0; e < 4; e++) { f[e] = (bf16)u0[e]; f[4+e] = (bf16)u1[e]; }
                    bfr[i] = f;
                }
            }
#pragma unroll
            for (int mi = 0; mi < 4; mi++)
#pragma unroll
                for (int ni = 0; ni < 4; ni++)
                    acc[mi][ni] = __builtin_amdgcn_mfma_f32_16x16x32_bf16(
                        af[mi], bfr[ni], acc[mi][ni], 0, 0, 0);
        }
        __syncthreads();
    }

    // epilogue: C/D layout col=lane&15, row=(lane>>4)*4+reg
    const float bscale = (blockIdx.z == 0) ? 1.0f : 0.0f;
#pragma unroll
    for (int mi = 0; mi < 4; mi++) {
#pragma unroll
        for (int ni = 0; ni < 4; ni++) {
            const int gcol = col0 + wn * 64 + ni * 16 + lo;
            const float bv = bias[gcol] * bscale;
#pragma unroll
            for (int r = 0; r < 4; r++) {
                const int grow = row0 + wm * 64 + mi * 16 + hi * 4 + r;
                float v = acc[mi][ni][r] + bv;
                if (MODE == 1) v = 0.5f * v * (1.0f + erff(v * 0.70710678118f));
                if (MODE == 2) {
                    atomicAdd(&resid[(size_t)grow * N + gcol], v);
                } else {
                    out[(size_t)grow * N + gcol] = (bf16)v;
                }
            }
        }
    }
}

// =====================================================================
// fp32 -> bf16 bulk convert (weights), 8 elems/lane
// =====================================================================
__global__ __launch_bounds__(256) void cvt_k(
    const float* __restrict__ src, bf16* __restrict__ dst)
{
    const int i = (blockIdx.x * 256 + threadIdx.x) * 8;
    const f32x4 a = *(const f32x4*)(src + i);
    const f32x4 b = *(const f32x4*)(src + i + 4);
    bf16x8 o;
#pragma unroll
    for (int e = 0; e < 4; e++) { o[e] = (bf16)a[e]; o[4 + e] = (bf16)b[e]; }
    *(bf16x8*)(dst + i) = o;
}

// =====================================================================
// LayerNorm: fp32 in [T,768] -> OutT out [T,768]; one wave per token
// =====================================================================
template<typename OutT>
__global__ __launch_bounds__(256) void ln_k(
    const float* __restrict__ x, const float* __restrict__ g,
    const float* __restrict__ b, OutT* __restrict__ out)
{
    const int wave = threadIdx.x >> 6, lane = threadIdx.x & 63;
    const int t = blockIdx.x * 4 + wave;
    const float* row = x + (size_t)t * C_;
    f32x4 v[3];
    float s = 0.f, ss = 0.f;
#pragma unroll
    for (int j = 0; j < 3; j++) {
        v[j] = *(const f32x4*)(row + (j * 64 + lane) * 4);
#pragma unroll
        for (int e = 0; e < 4; e++) { s += v[j][e]; ss += v[j][e] * v[j][e]; }
    }
#pragma unroll
    for (int off = 32; off > 0; off >>= 1) {
        s  += __shfl_xor(s, off);
        ss += __shfl_xor(ss, off);
    }
    const float mu  = s * (1.f / 768.f);
    const float var = ss * (1.f / 768.f) - mu * mu;
    const float rs  = rsqrtf(var + 1e-5f);
    OutT* orow = out + (size_t)t * C_;
#pragma unroll
    for (int j = 0; j < 3; j++) {
        const f32x4 gv = *(const f32x4*)(g + (j * 64 + lane) * 4);
        const f32x4 bv = *(const f32x4*)(b + (j * 64 + lane) * 4);
#pragma unroll
        for (int e = 0; e < 4; e++)
            orow[(j * 64 + lane) * 4 + e] = (OutT)((v[j][e] - mu) * rs * gv[e] + bv[e]);
    }
}

// =====================================================================
// x + pos_x (fp32) -> fp32 residual stream
// =====================================================================
__global__ __launch_bounds__(256) void addpos_k(
    const float* __restrict__ x, const float* __restrict__ p, float* __restrict__ o)
{
    const int i = (blockIdx.x * 256 + threadIdx.x) * 4;
    const f32x4 xv = *(const f32x4*)(x + i);
    const f32x4 pv = *(const f32x4*)(p + i);
    f32x4 ov;
#pragma unroll
    for (int e = 0; e < 4; e++) ov[e] = xv[e] + pv[e];
    *(f32x4*)(o + i) = ov;
}

// =====================================================================
// Flash attention: qkv bf16 [4096, 2304] -> out bf16 [4096, 768]
// block = (qtile of 64 rows, b*H+h); 4 waves, wave w owns q rows w*16..+16
// KVBLK=128: halves barriers, shfl reductions and O-rescales per key
// vs the previous 64-key tiles. Q pre-scaled by 0.125 (exact in bf16).
// LDS rows padded (+8 bf16) -> fragment reads ~2-way (free).
// V^T staged via transposed coalesced ushort loads; P streamed to
// wave-private lP (no barrier on that path). 2 barriers per 128 keys.
// LDS total 53 KB -> 3 blocks/CU (matches GEMM occupancy regime).
// =====================================================================
#define SKD_ 72     // lK row stride  [key][d]
#define SVK_ 136    // lV row stride  [d][key]  (128+8)
#define SPK_ 136    // lP row stride  [q][key]
__global__ __launch_bounds__(256) void attn_k(
    const bf16* __restrict__ qkv, bf16* __restrict__ out)
{
    const int qt = blockIdx.x;          // 0..15
    const int bh = blockIdx.y;          // 0..47
    const int b = bh / H_, h = bh % H_;
    const int lane = threadIdx.x & 63, wave = threadIdx.x >> 6;
    const int lo = lane & 15, hi = lane >> 4;

    __shared__ __align__(16) bf16 lK[128 * SKD_];     // 18432 B [key][d]
    __shared__ __align__(16) bf16 lV[64 * SVK_];      // 17408 B V^T [d][key]
    __shared__ __align__(16) bf16 lP[4][16 * SPK_];   // 17408 B per-wave P

    const size_t tokbase = (size_t)b * N_;

    // persistent Q A-fragments, pre-scaled by 1/sqrt(HD)=0.125 (exact pow2)
    const bf16* qptr = qkv + (tokbase + qt * 64 + wave * 16 + lo) * (3 * C_) + h * HD_;
    bf16x8 qf0 = *(const bf16x8*)(qptr + hi * 8);
    bf16x8 qf1 = *(const bf16x8*)(qptr + 32 + hi * 8);
#pragma unroll
    for (int e = 0; e < 8; e++) {
        qf0[e] = (bf16)((float)qf0[e] * 0.125f);
        qf1[e] = (bf16)((float)qf1[e] * 0.125f);
    }

    float m_r[4], l_r[4];
    f32x4 oacc[4];
#pragma unroll
    for (int r = 0; r < 4; r++) { m_r[r] = -1e30f; l_r[r] = 0.f; }
#pragma unroll
    for (int di = 0; di < 4; di++) oacc[di] = (f32x4){0.f, 0.f, 0.f, 0.f};

    for (int kt = 0; kt < 8; ++kt) {
        const int kb0 = kt * 128;
        // ---- K: vectorized [key][d] staging (128 keys x 8 chunks) ----
#pragma unroll
        for (int r = 0; r < 4; ++r) {
            const int chunk = r * 256 + threadIdx.x;     // 0..1023
            const int key = chunk >> 3, dc = chunk & 7;
            const bf16* kp = qkv + (tokbase + kb0 + key) * (3 * C_) + C_ + h * HD_ + dc * 8;
            *(bf16x8*)(lK + key * SKD_ + dc * 8) = *(const bf16x8*)kp;
        }
        // ---- V^T: transposed coalesced loads (lane d, 8 keys/chunk) ----
#pragma unroll
        for (int r = 0; r < 4; ++r) {
            const int chunk = r * 256 + threadIdx.x;     // 0..1023
            const int d = chunk & 63, kg = chunk >> 6;   // kg 0..15
            const bf16* vp = qkv + (tokbase + kb0 + kg * 8) * (3 * C_)
                           + 2 * C_ + h * HD_ + d;
            bf16x8 tv;
#pragma unroll
            for (int i = 0; i < 8; i++) tv[i] = vp[(size_t)i * (3 * C_)];
            *(bf16x8*)(lV + d * SVK_ + kg * 8) = tv;
        }
        __syncthreads();

        // ---- S = Q @ K^T (per wave: 16 q x 128 keys), already scaled ----
        f32x4 sacc[8];
#pragma unroll
        for (int kb = 0; kb < 8; kb++) {
            const bf16x8 b0 = *(const bf16x8*)(lK + (kb * 16 + lo) * SKD_ + hi * 8);
            const bf16x8 b1 = *(const bf16x8*)(lK + (kb * 16 + lo) * SKD_ + 32 + hi * 8);
            f32x4 a = (f32x4){0.f, 0.f, 0.f, 0.f};
            a = __builtin_amdgcn_mfma_f32_16x16x32_bf16(qf0, b0, a, 0, 0, 0);
            a = __builtin_amdgcn_mfma_f32_16x16x32_bf16(qf1, b1, a, 0, 0, 0);
            sacc[kb] = a;
        }

        // ---- online softmax (row r = q row hi*4+r; reduce over lo) ----
        float tm[4], mn[4], alpha[4], ts[4];
#pragma unroll
        for (int r = 0; r < 4; r++) {
            float a0 = fmaxf(fmaxf(sacc[0][r], sacc[1][r]),
                             fmaxf(sacc[2][r], sacc[3][r]));
            float a1 = fmaxf(fmaxf(sacc[4][r], sacc[5][r]),
                             fmaxf(sacc[6][r], sacc[7][r]));
            tm[r] = fmaxf(a0, a1);
#pragma unroll
            for (int off = 1; off < 16; off <<= 1)
                tm[r] = fmaxf(tm[r], __shfl_xor(tm[r], off));
            mn[r] = fmaxf(m_r[r], tm[r]);
            alpha[r] = __expf(m_r[r] - mn[r]);
            ts[r] = 0.f;
        }
        // stream: exp -> wave-private lP -> partial sum (no ps[][] array)
#pragma unroll
        for (int kb = 0; kb < 8; kb++)
#pragma unroll
            for (int r = 0; r < 4; r++) {
                const float p = __expf(sacc[kb][r] - mn[r]);
                lP[wave][(hi * 4 + r) * SPK_ + kb * 16 + lo] = (bf16)p;
                ts[r] += p;
            }
#pragma unroll
        for (int r = 0; r < 4; r++) {
#pragma unroll
            for (int off = 1; off < 16; off <<= 1)
                ts[r] += __shfl_xor(ts[r], off);
            l_r[r] = l_r[r] * alpha[r] + ts[r];
            m_r[r] = mn[r];
        }
#pragma unroll
        for (int di = 0; di < 4; di++)
#pragma unroll
            for (int r = 0; r < 4; r++) oacc[di][r] *= alpha[r];

        // ---- PV: P A-frags (wave-private, no barrier needed) ----
        bf16x8 pa[4];
#pragma unroll
        for (int s = 0; s < 4; s++)
            pa[s] = *(const bf16x8*)(&lP[wave][lo * SPK_ + s * 32 + hi * 8]);
#pragma unroll
        for (int di = 0; di < 4; di++) {
#pragma unroll
            for (int s = 0; s < 4; s++) {
                const bf16x8 v = *(const bf16x8*)(lV + (di * 16 + lo) * SVK_ + s * 32 + hi * 8);
                oacc[di] = __builtin_amdgcn_mfma_f32_16x16x32_bf16(pa[s], v, oacc[di], 0, 0, 0);
            }
        }
        __syncthreads();
    }

    // ---- epilogue: O / l ----
#pragma unroll
    for (int di = 0; di < 4; di++)
#pragma unroll
        for (int r = 0; r < 4; r++) {
            const size_t tok = tokbase + qt * 64 + wave * 16 + hi * 4 + r;
            out[tok * C_ + h * HD_ + di * 16 + lo] = (bf16)(oacc[di][r] / l_r[r]);
        }
}

// =====================================================================
extern "C" void kernel_launch(void* const* d_in, const int* in_sizes, int n_in,
                              void* d_out, int out_size, void* d_ws, size_t ws_size,
                              hipStream_t stream)
{
    const float* x      = (const float*)d_in[0];
    const float* pos_x  = (const float*)d_in[1];
    const float* qkv_w  = (const float*)d_in[2];
    const float* qkv_b  = (const float*)d_in[3];
    const float* proj_w = (const float*)d_in[4];
    const float* proj_b = (const float*)d_in[5];
    const float* fc1_w  = (const float*)d_in[6];
    const float* fc1_b  = (const float*)d_in[7];
    const float* fc2_w  = (const float*)d_in[8];
    const float* fc2_b  = (const float*)d_in[9];
    const float* ln1_g  = (const float*)d_in[10];
    const float* ln1_b  = (const float*)d_in[11];
    const float* ln2_g  = (const float*)d_in[12];
    const float* ln2_b  = (const float*)d_in[13];
    const float* nf_g   = (const float*)d_in[14];
    const float* nf_b   = (const float*)d_in[15];

    char* ws = (char*)d_ws;
    float* xres  = (float*)(ws);                         // 12,582,912 B
    bf16* hbuf   = (bf16*)(ws + 12582912);               //  6,291,456
    bf16* qkvbuf = (bf16*)(ws + 18874368);               // 18,874,368
    bf16* attno  = (bf16*)(ws + 37748736);               //  6,291,456
    bf16* hid    = (bf16*)(ws + 44040192);               // 25,165,824 (end 69,206,016)
    bf16* wq     = (bf16*)(ws + 69206016);               // 42,467,328
    bf16* wp     = (bf16*)(ws + 111673344);              // 14,155,776
    bf16* w1     = (bf16*)(ws + 125829120);              // 56,623,104
    bf16* w2     = (bf16*)(ws + 182452224);              // 56,623,104 (end 239,075,328)
    const bool usebf16 = ws_size >= (size_t)239075328;

    addpos_k<<<T_ * C_ / 4 / 256, 256, 0, stream>>>(x, pos_x, xres);

    if (usebf16) {
        cvt_k<<<D_ * 3 * C_ * C_ / 2048, 256, 0, stream>>>(qkv_w, wq);
        cvt_k<<<D_ * C_ * C_ / 2048, 256, 0, stream>>>(proj_w, wp);
        cvt_k<<<D_ * FF_ * C_ / 2048, 256, 0, stream>>>(fc1_w, w1);
        cvt_k<<<D_ * C_ * FF_ / 2048, 256, 0, stream>>>(fc2_w, w2);
    }

    for (int L = 0; L < D_; ++L) {
        ln_k<bf16><<<T_ / 4, 256, 0, stream>>>(xres, ln1_g + L * C_, ln1_b + L * C_, hbuf);
        if (usebf16) {
            gemm_bt<bf16,0><<<dim3(T_/128, (3*C_)/128, 1), 256, 0, stream>>>(
                hbuf, wq + (size_t)L * 3 * C_ * C_, qkv_b + (size_t)L * 3 * C_,
                qkvbuf, nullptr, T_, 3 * C_, C_, C_);
        } else {
            gemm_bt<float,0><<<dim3(T_/128, (3*C_)/128, 1), 256, 0, stream>>>(
                hbuf, qkv_w + (size_t)L * 3 * C_ * C_, qkv_b + (size_t)L * 3 * C_,
                qkvbuf, nullptr, T_, 3 * C_, C_, C_);
        }
        attn_k<<<dim3(N_ / 64, B_ * H_), 256, 0, stream>>>(qkvbuf, attno);
        if (usebf16) {
            gemm_bt<bf16,2><<<dim3(T_/128, C_/128, 2), 256, 0, stream>>>(
                attno, wp + (size_t)L * C_ * C_, proj_b + (size_t)L * C_,
                nullptr, xres, T_, C_, C_, C_ / 2);
        } else {
            gemm_bt<float,2><<<dim3(T_/128, C_/128, 2), 256, 0, stream>>>(
                attno, proj_w + (size_t)L * C_ * C_, proj_b + (size_t)L * C_,
                nullptr, xres, T_, C_, C_, C_ / 2);
        }
        ln_k<bf16><<<T_ / 4, 256, 0, stream>>>(xres, ln2_g + L * C_, ln2_b + L * C_, hbuf);
        if (usebf16) {
            gemm_bt<bf16,1><<<dim3(T_/128, FF_/128, 1), 256, 0, stream>>>(
                hbuf, w1 + (size_t)L * FF_ * C_, fc1_b + (size_t)L * FF_,
                hid, nullptr, T_, FF_, C_, C_);
            gemm_bt<bf16,2><<<dim3(T_/128, C_/128, 2), 256, 0, stream>>>(
                hid, w2 + (size_t)L * C_ * FF_, fc2_b + (size_t)L * C_,
                nullptr, xres, T_, C_, FF_, FF_ / 2);
        } else {
            gemm_bt<float,1><<<dim3(T_/128, FF_/128, 1), 256, 0, stream>>>(
                hbuf, fc1_w + (size_t)L * FF_ * C_, fc1_b + (size_t)L * FF_,
                hid, nullptr, T_, FF_, C_, C_);
            gemm_bt<float,2><<<dim3(T_/128, C_/128, 2), 256, 0, stream>>>(
                hid, fc2_w + (size_t)L * C_ * FF_, fc2_b + (size_t)L * C_,
                nullptr, xres, T_, C_, FF_, FF_ / 2);
        }
    }
    ln_k<float><<<T_ / 4, 256, 0, stream>>>(xres, nf_g, nf_b, (float*)d_out);
}

// Round 3
// 2556.621 us; speedup vs baseline: 1.1510x; 1.0352x over previous
//
#include <hip/hip_runtime.h>
#include <hip/hip_bf16.h>
#include <math.h>

typedef __bf16 bf16;
typedef __bf16 bf16x8 __attribute__((ext_vector_type(8)));
typedef __bf16 bf16x4 __attribute__((ext_vector_type(4)));
typedef float  f32x4  __attribute__((ext_vector_type(4)));

#define B_  4
#define N_  1024
#define C_  768
#define H_  12
#define HD_ 64
#define FF_ 3072
#define T_  (B_*N_)      // 4096 tokens
#define D_  12

// ---- async global->LDS, 16B per lane, wave-uniform LDS base ----
__device__ __forceinline__ void gld_lds16(const void* g, void* l) {
    __builtin_amdgcn_global_load_lds(
        (const __attribute__((address_space(1))) void*)g,
        (__attribute__((address_space(3))) void*)l, 16, 0, 0);
}

// =====================================================================
// GEMM:  out[M,N] = A[M,K] @ Bt[N,K]^T + bias
//   A: bf16 activations. WT = bf16 (preconverted weights) or float
//   (fallback: swizzled fp32 staging + in-loop cvt).
// MODE 0: store bf16   MODE 1: GELU(exact) then store bf16
// MODE 2: resid[M,N] (fp32) atomicAdd (split-K safe; bias only on z==0)
// 128x128 tile, BK=64, 4 waves 2x2, each wave 64x64 via 4x4 16x16x32
// MFMA, two K=32 sub-steps per stage. LDS XOR-swizzle both-sides.
// 1-D grid + XCD swizzle (T1): consecutive remapped ids share the SAME
// weight panel (by) and land on the SAME XCD -> B-panel fetched ~1x from
// HBM instead of up to 8x (one per XCD). All grids divisible by 8.
// =====================================================================
template<typename WT, int MODE>
__global__ __launch_bounds__(256) void gemm_bt(
    const bf16* __restrict__ A, const WT* __restrict__ Bt,
    const float* __restrict__ bias, bf16* __restrict__ out,
    float* __restrict__ resid, int M, int N, int Kfull, int Ks)
{
    __shared__ __align__(16) bf16 lA[128*64];   // 16 KB  [row][64k] swizzled
    __shared__ __align__(16) WT   lB[128*64];   // 16 KB bf16 / 32 KB f32
    const int tid  = threadIdx.x;
    const int lane = tid & 63, wave = tid >> 6;
    const int lo = lane & 15, hi = lane >> 4;
    const int wm = wave & 1, wn = wave >> 1;

    // XCD swizzle: nblk % 8 == 0 for all call sites -> bijective
    const int nblk = gridDim.x;
    const int id2  = (blockIdx.x & 7) * (nblk >> 3) + (blockIdx.x >> 3);
    const int gx = M >> 7, gy = N >> 7;
    const int bx  = id2 % gx;
    const int byz = id2 / gx;
    const int by  = byz % gy;
    const int bz  = byz / gy;
    const int row0 = bx * 128, col0 = by * 128;
    const int k0base = bz * Ks;

    f32x4 acc[4][4];
#pragma unroll
    for (int i = 0; i < 4; i++)
#pragma unroll
        for (int j = 0; j < 4; j++) acc[i][j] = (f32x4){0.f, 0.f, 0.f, 0.f};

    for (int k0 = k0base; k0 < k0base + Ks; k0 += 64) {
        // A tile: 1024 chunks x 16B (8 bf16), LDS linear [row][8 chunks],
        // global source chunk = kc ^ (row&7)
#pragma unroll
        for (int r = 0; r < 4; ++r) {
            const int cb    = r * 256 + wave * 64;   // wave-uniform base
            const int chunk = cb + lane;
            const int rw = chunk >> 3, kc = chunk & 7;
            const int kcs = kc ^ (rw & 7);
            gld_lds16(A + (size_t)(row0 + rw) * Kfull + k0 + kcs * 8, lA + cb * 8);
        }
        if constexpr (sizeof(WT) == 2) {
#pragma unroll
            for (int r = 0; r < 4; ++r) {
                const int cb    = r * 256 + wave * 64;
                const int chunk = cb + lane;
                const int rw = chunk >> 3, kc = chunk & 7;
                const int kcs = kc ^ (rw & 7);
                gld_lds16(Bt + (size_t)(col0 + rw) * Kfull + k0 + kcs * 8,
                          (bf16*)lB + cb * 8);
            }
        } else {
            // B tile fp32: 2048 chunks x 16B, swizzle kc ^ ((row&7)<<1)
#pragma unroll
            for (int r = 0; r < 8; ++r) {
                const int cb    = r * 256 + wave * 64;
                const int chunk = cb + lane;
                const int rw = chunk >> 4, kc = chunk & 15;
                const int kcs = kc ^ ((rw & 7) << 1);
                gld_lds16(Bt + (size_t)(col0 + rw) * Kfull + k0 + kcs * 4,
                          (float*)lB + cb * 4);
            }
        }
        __syncthreads();
        // two K=32 sub-steps; NOT unrolled so fragment liveness stays at
        // the m97 level (~164 VGPR, 3 waves/SIMD) — avoid m132 cliff
#pragma unroll 1
        for (int s = 0; s < 2; ++s) {
            bf16x8 af[4], bfr[4];
#pragma unroll
            for (int i = 0; i < 4; i++) {
                const int rowA = wm * 64 + i * 16 + lo;
                const int ca = (s * 4 + hi) ^ (lo & 7);
                af[i] = *(const bf16x8*)(lA + rowA * 64 + ca * 8);
            }
#pragma unroll
            for (int i = 0; i < 4; i++) {
                const int rowB = wn * 64 + i * 16 + lo;
                if constexpr (sizeof(WT) == 2) {
                    const int cb = (s * 4 + hi) ^ (lo & 7);
                    bfr[i] = *(const bf16x8*)((const bf16*)lB + rowB * 64 + cb * 8);
                } else {
                    const float* base = (const float*)lB + rowB * 64;
                    const int c0 = (s * 8 + hi * 2) ^ ((lo & 7) << 1);
                    const f32x4 u0 = *(const f32x4*)(base + c0 * 4);
                    const f32x4 u1 = *(const f32x4*)(base + (c0 + 1) * 4);
                    bf16x8 f;
#pragma unroll
                    for (int e = 0; e < 4; e++) { f[e] = (bf16)u0[e]; f[4+e] = (bf16)u1[e]; }
                    bfr[i] = f;
                }
            }
#pragma unroll
            for (int mi = 0; mi < 4; mi++)
#pragma unroll
                for (int ni = 0; ni < 4; ni++)
                    acc[mi][ni] = __builtin_amdgcn_mfma_f32_16x16x32_bf16(
                        af[mi], bfr[ni], acc[mi][ni], 0, 0, 0);
        }
        __syncthreads();
    }

    // epilogue: C/D layout col=lane&15, row=(lane>>4)*4+reg
    const float bscale = (bz == 0) ? 1.0f : 0.0f;
#pragma unroll
    for (int mi = 0; mi < 4; mi++) {
#pragma unroll
        for (int ni = 0; ni < 4; ni++) {
            const int gcol = col0 + wn * 64 + ni * 16 + lo;
            const float bv = bias[gcol] * bscale;
#pragma unroll
            for (int r = 0; r < 4; r++) {
                const int grow = row0 + wm * 64 + mi * 16 + hi * 4 + r;
                float v = acc[mi][ni][r] + bv;
                if (MODE == 1) v = 0.5f * v * (1.0f + erff(v * 0.70710678118f));
                if (MODE == 2) {
                    atomicAdd(&resid[(size_t)grow * N + gcol], v);
                } else {
                    out[(size_t)grow * N + gcol] = (bf16)v;
                }
            }
        }
    }
}

// =====================================================================
// fp32 -> bf16 bulk convert (weights), 8 elems/lane
// =====================================================================
__global__ __launch_bounds__(256) void cvt_k(
    const float* __restrict__ src, bf16* __restrict__ dst)
{
    const int i = (blockIdx.x * 256 + threadIdx.x) * 8;
    const f32x4 a = *(const f32x4*)(src + i);
    const f32x4 b = *(const f32x4*)(src + i + 4);
    bf16x8 o;
#pragma unroll
    for (int e = 0; e < 4; e++) { o[e] = (bf16)a[e]; o[4 + e] = (bf16)b[e]; }
    *(bf16x8*)(dst + i) = o;
}

// =====================================================================
// LayerNorm: fp32 in [T,768] -> OutT out [T,768]; one wave per token
// =====================================================================
template<typename OutT>
__global__ __launch_bounds__(256) void ln_k(
    const float* __restrict__ x, const float* __restrict__ g,
    const float* __restrict__ b, OutT* __restrict__ out)
{
    const int wave = threadIdx.x >> 6, lane = threadIdx.x & 63;
    const int t = blockIdx.x * 4 + wave;
    const float* row = x + (size_t)t * C_;
    f32x4 v[3];
    float s = 0.f, ss = 0.f;
#pragma unroll
    for (int j = 0; j < 3; j++) {
        v[j] = *(const f32x4*)(row + (j * 64 + lane) * 4);
#pragma unroll
        for (int e = 0; e < 4; e++) { s += v[j][e]; ss += v[j][e] * v[j][e]; }
    }
#pragma unroll
    for (int off = 32; off > 0; off >>= 1) {
        s  += __shfl_xor(s, off);
        ss += __shfl_xor(ss, off);
    }
    const float mu  = s * (1.f / 768.f);
    const float var = ss * (1.f / 768.f) - mu * mu;
    const float rs  = rsqrtf(var + 1e-5f);
    OutT* orow = out + (size_t)t * C_;
#pragma unroll
    for (int j = 0; j < 3; j++) {
        const f32x4 gv = *(const f32x4*)(g + (j * 64 + lane) * 4);
        const f32x4 bv = *(const f32x4*)(b + (j * 64 + lane) * 4);
#pragma unroll
        for (int e = 0; e < 4; e++)
            orow[(j * 64 + lane) * 4 + e] = (OutT)((v[j][e] - mu) * rs * gv[e] + bv[e]);
    }
}

// =====================================================================
// x + pos_x (fp32) -> fp32 residual stream
// =====================================================================
__global__ __launch_bounds__(256) void addpos_k(
    const float* __restrict__ x, const float* __restrict__ p, float* __restrict__ o)
{
    const int i = (blockIdx.x * 256 + threadIdx.x) * 4;
    const f32x4 xv = *(const f32x4*)(x + i);
    const f32x4 pv = *(const f32x4*)(p + i);
    f32x4 ov;
#pragma unroll
    for (int e = 0; e < 4; e++) ov[e] = xv[e] + pv[e];
    *(f32x4*)(o + i) = ov;
}

// =====================================================================
// Flash attention: qkv bf16 [4096, 2304] -> out bf16 [4096, 768]
// 1-D grid (768) + XCD swizzle: the 16 q-tile blocks sharing one (b,h)
// K/V slice (256 KB, L2-resident) are grouped on the same XCD.
// KVBLK=128, 4 waves, wave w owns q rows w*16..+16.
// T13 defer-max: skip max shfl-tree + alpha rescale when the tile's
// partial max stays within m_r+8 on all lanes (wave-uniform branch;
// P bounded by e^8, fp32 l/oacc have headroom; first tile always full).
// =====================================================================
#define SKD_ 72     // lK row stride  [key][d]
#define SVK_ 136    // lV row stride  [d][key]  (128+8)
#define SPK_ 136    // lP row stride  [q][key]
__global__ __launch_bounds__(256) void attn_k(
    const bf16* __restrict__ qkv, bf16* __restrict__ out)
{
    const int id2 = (blockIdx.x & 7) * 96 + (blockIdx.x >> 3);  // 768 blocks
    const int qt = id2 & 15;            // 0..15
    const int bh = id2 >> 4;            // 0..47
    const int b = bh / H_, h = bh % H_;
    const int lane = threadIdx.x & 63, wave = threadIdx.x >> 6;
    const int lo = lane & 15, hi = lane >> 4;

    __shared__ __align__(16) bf16 lK[128 * SKD_];     // 18432 B [key][d]
    __shared__ __align__(16) bf16 lV[64 * SVK_];      // 17408 B V^T [d][key]
    __shared__ __align__(16) bf16 lP[4][16 * SPK_];   // 17408 B per-wave P

    const size_t tokbase = (size_t)b * N_;

    // persistent Q A-fragments, pre-scaled by 1/sqrt(HD)=0.125 (exact pow2)
    const bf16* qptr = qkv + (tokbase + qt * 64 + wave * 16 + lo) * (3 * C_) + h * HD_;
    bf16x8 qf0 = *(const bf16x8*)(qptr + hi * 8);
    bf16x8 qf1 = *(const bf16x8*)(qptr + 32 + hi * 8);
#pragma unroll
    for (int e = 0; e < 8; e++) {
        qf0[e] = (bf16)((float)qf0[e] * 0.125f);
        qf1[e] = (bf16)((float)qf1[e] * 0.125f);
    }

    float m_r[4], l_r[4];
    f32x4 oacc[4];
#pragma unroll
    for (int r = 0; r < 4; r++) { m_r[r] = -1e30f; l_r[r] = 0.f; }
#pragma unroll
    for (int di = 0; di < 4; di++) oacc[di] = (f32x4){0.f, 0.f, 0.f, 0.f};

    for (int kt = 0; kt < 8; ++kt) {
        const int kb0 = kt * 128;
        // ---- K: vectorized [key][d] staging (128 keys x 8 chunks) ----
#pragma unroll
        for (int r = 0; r < 4; ++r) {
            const int chunk = r * 256 + threadIdx.x;     // 0..1023
            const int key = chunk >> 3, dc = chunk & 7;
            const bf16* kp = qkv + (tokbase + kb0 + key) * (3 * C_) + C_ + h * HD_ + dc * 8;
            *(bf16x8*)(lK + key * SKD_ + dc * 8) = *(const bf16x8*)kp;
        }
        // ---- V^T: transposed coalesced loads (lane d, 8 keys/chunk) ----
#pragma unroll
        for (int r = 0; r < 4; ++r) {
            const int chunk = r * 256 + threadIdx.x;     // 0..1023
            const int d = chunk & 63, kg = chunk >> 6;   // kg 0..15
            const bf16* vp = qkv + (tokbase + kb0 + kg * 8) * (3 * C_)
                           + 2 * C_ + h * HD_ + d;
            bf16x8 tv;
#pragma unroll
            for (int i = 0; i < 8; i++) tv[i] = vp[(size_t)i * (3 * C_)];
            *(bf16x8*)(lV + d * SVK_ + kg * 8) = tv;
        }
        __syncthreads();

        // ---- S = Q @ K^T (per wave: 16 q x 128 keys), already scaled ----
        f32x4 sacc[8];
#pragma unroll
        for (int kb = 0; kb < 8; kb++) {
            const bf16x8 b0 = *(const bf16x8*)(lK + (kb * 16 + lo) * SKD_ + hi * 8);
            const bf16x8 b1 = *(const bf16x8*)(lK + (kb * 16 + lo) * SKD_ + 32 + hi * 8);
            f32x4 a = (f32x4){0.f, 0.f, 0.f, 0.f};
            a = __builtin_amdgcn_mfma_f32_16x16x32_bf16(qf0, b0, a, 0, 0, 0);
            a = __builtin_amdgcn_mfma_f32_16x16x32_bf16(qf1, b1, a, 0, 0, 0);
            sacc[kb] = a;
        }

        // ---- online softmax, defer-max (row r = q row hi*4+r) ----
        float pm[4], mn[4], ts[4];
#pragma unroll
        for (int r = 0; r < 4; r++) {
            float a0 = fmaxf(fmaxf(sacc[0][r], sacc[1][r]),
                             fmaxf(sacc[2][r], sacc[3][r]));
            float a1 = fmaxf(fmaxf(sacc[4][r], sacc[5][r]),
                             fmaxf(sacc[6][r], sacc[7][r]));
            pm[r] = fmaxf(a0, a1);
            ts[r] = 0.f;
        }
        const int okd = (pm[0] <= m_r[0] + 8.f) && (pm[1] <= m_r[1] + 8.f)
                     && (pm[2] <= m_r[2] + 8.f) && (pm[3] <= m_r[3] + 8.f);
        const bool defer = __all(okd);
        if (defer) {
#pragma unroll
            for (int r = 0; r < 4; r++) mn[r] = m_r[r];
        } else {
#pragma unroll
            for (int r = 0; r < 4; r++) {
                float tm = pm[r];
#pragma unroll
                for (int off = 1; off < 16; off <<= 1)
                    tm = fmaxf(tm, __shfl_xor(tm, off));
                mn[r] = fmaxf(m_r[r], tm);
            }
        }
        // stream: exp -> wave-private lP -> partial sum
#pragma unroll
        for (int kb = 0; kb < 8; kb++)
#pragma unroll
            for (int r = 0; r < 4; r++) {
                const float p = __expf(sacc[kb][r] - mn[r]);
                lP[wave][(hi * 4 + r) * SPK_ + kb * 16 + lo] = (bf16)p;
                ts[r] += p;
            }
#pragma unroll
        for (int r = 0; r < 4; r++)
#pragma unroll
            for (int off = 1; off < 16; off <<= 1)
                ts[r] += __shfl_xor(ts[r], off);
        if (defer) {
#pragma unroll
            for (int r = 0; r < 4; r++) l_r[r] += ts[r];
        } else {
            float alpha[4];
#pragma unroll
            for (int r = 0; r < 4; r++) {
                alpha[r] = __expf(m_r[r] - mn[r]);
                l_r[r] = l_r[r] * alpha[r] + ts[r];
                m_r[r] = mn[r];
            }
#pragma unroll
            for (int di = 0; di < 4; di++)
#pragma unroll
                for (int r = 0; r < 4; r++) oacc[di][r] *= alpha[r];
        }

        // ---- PV: P A-frags (wave-private, no barrier needed) ----
        bf16x8 pa[4];
#pragma unroll
        for (int s = 0; s < 4; s++)
            pa[s] = *(const bf16x8*)(&lP[wave][lo * SPK_ + s * 32 + hi * 8]);
#pragma unroll
        for (int di = 0; di < 4; di++) {
#pragma unroll
            for (int s = 0; s < 4; s++) {
                const bf16x8 v = *(const bf16x8*)(lV + (di * 16 + lo) * SVK_ + s * 32 + hi * 8);
                oacc[di] = __builtin_amdgcn_mfma_f32_16x16x32_bf16(pa[s], v, oacc[di], 0, 0, 0);
            }
        }
        __syncthreads();
    }

    // ---- epilogue: O * (1/l) ----
    float il[4];
#pragma unroll
    for (int r = 0; r < 4; r++) il[r] = 1.0f / l_r[r];
#pragma unroll
    for (int di = 0; di < 4; di++)
#pragma unroll
        for (int r = 0; r < 4; r++) {
            const size_t tok = tokbase + qt * 64 + wave * 16 + hi * 4 + r;
            out[tok * C_ + h * HD_ + di * 16 + lo] = (bf16)(oacc[di][r] * il[r]);
        }
}

// =====================================================================
extern "C" void kernel_launch(void* const* d_in, const int* in_sizes, int n_in,
                              void* d_out, int out_size, void* d_ws, size_t ws_size,
                              hipStream_t stream)
{
    const float* x      = (const float*)d_in[0];
    const float* pos_x  = (const float*)d_in[1];
    const float* qkv_w  = (const float*)d_in[2];
    const float* qkv_b  = (const float*)d_in[3];
    const float* proj_w = (const float*)d_in[4];
    const float* proj_b = (const float*)d_in[5];
    const float* fc1_w  = (const float*)d_in[6];
    const float* fc1_b  = (const float*)d_in[7];
    const float* fc2_w  = (const float*)d_in[8];
    const float* fc2_b  = (const float*)d_in[9];
    const float* ln1_g  = (const float*)d_in[10];
    const float* ln1_b  = (const float*)d_in[11];
    const float* ln2_g  = (const float*)d_in[12];
    const float* ln2_b  = (const float*)d_in[13];
    const float* nf_g   = (const float*)d_in[14];
    const float* nf_b   = (const float*)d_in[15];

    char* ws = (char*)d_ws;
    float* xres  = (float*)(ws);                         // 12,582,912 B
    bf16* hbuf   = (bf16*)(ws + 12582912);               //  6,291,456
    bf16* qkvbuf = (bf16*)(ws + 18874368);               // 18,874,368
    bf16* attno  = (bf16*)(ws + 37748736);               //  6,291,456
    bf16* hid    = (bf16*)(ws + 44040192);               // 25,165,824 (end 69,206,016)
    bf16* wq     = (bf16*)(ws + 69206016);               // 42,467,328
    bf16* wp     = (bf16*)(ws + 111673344);              // 14,155,776
    bf16* w1     = (bf16*)(ws + 125829120);              // 56,623,104
    bf16* w2     = (bf16*)(ws + 182452224);              // 56,623,104 (end 239,075,328)
    const bool usebf16 = ws_size >= (size_t)239075328;

    addpos_k<<<T_ * C_ / 4 / 256, 256, 0, stream>>>(x, pos_x, xres);

    if (usebf16) {
        cvt_k<<<D_ * 3 * C_ * C_ / 2048, 256, 0, stream>>>(qkv_w, wq);
        cvt_k<<<D_ * C_ * C_ / 2048, 256, 0, stream>>>(proj_w, wp);
        cvt_k<<<D_ * FF_ * C_ / 2048, 256, 0, stream>>>(fc1_w, w1);
        cvt_k<<<D_ * C_ * FF_ / 2048, 256, 0, stream>>>(fc2_w, w2);
    }

    // 1-D grids (XCD swizzle decode inside kernels)
    const int g_qkv  = (T_/128) * ((3*C_)/128);      // 576
    const int g_proj = (T_/128) * (C_/128) * 2;      // 384
    const int g_fc1  = (T_/128) * (FF_/128);         // 768
    const int g_fc2  = (T_/128) * (C_/128) * 2;      // 384

    for (int L = 0; L < D_; ++L) {
        ln_k<bf16><<<T_ / 4, 256, 0, stream>>>(xres, ln1_g + L * C_, ln1_b + L * C_, hbuf);
        if (usebf16) {
            gemm_bt<bf16,0><<<g_qkv, 256, 0, stream>>>(
                hbuf, wq + (size_t)L * 3 * C_ * C_, qkv_b + (size_t)L * 3 * C_,
                qkvbuf, nullptr, T_, 3 * C_, C_, C_);
        } else {
            gemm_bt<float,0><<<g_qkv, 256, 0, stream>>>(
                hbuf, qkv_w + (size_t)L * 3 * C_ * C_, qkv_b + (size_t)L * 3 * C_,
                qkvbuf, nullptr, T_, 3 * C_, C_, C_);
        }
        attn_k<<<N_ / 64 * B_ * H_, 256, 0, stream>>>(qkvbuf, attno);
        if (usebf16) {
            gemm_bt<bf16,2><<<g_proj, 256, 0, stream>>>(
                attno, wp + (size_t)L * C_ * C_, proj_b + (size_t)L * C_,
                nullptr, xres, T_, C_, C_, C_ / 2);
        } else {
            gemm_bt<float,2><<<g_proj, 256, 0, stream>>>(
                attno, proj_w + (size_t)L * C_ * C_, proj_b + (size_t)L * C_,
                nullptr, xres, T_, C_, C_, C_ / 2);
        }
        ln_k<bf16><<<T_ / 4, 256, 0, stream>>>(xres, ln2_g + L * C_, ln2_b + L * C_, hbuf);
        if (usebf16) {
            gemm_bt<bf16,1><<<g_fc1, 256, 0, stream>>>(
                hbuf, w1 + (size_t)L * FF_ * C_, fc1_b + (size_t)L * FF_,
                hid, nullptr, T_, FF_, C_, C_);
            gemm_bt<bf16,2><<<g_fc2, 256, 0, stream>>>(
                hid, w2 + (size_t)L * C_ * FF_, fc2_b + (size_t)L * C_,
                nullptr, xres, T_, C_, FF_, FF_ / 2);
        } else {
            gemm_bt<float,1><<<g_fc1, 256, 0, stream>>>(
                hbuf, fc1_w + (size_t)L * FF_ * C_, fc1_b + (size_t)L * FF_,
                hid, nullptr, T_, FF_, C_, C_);
            gemm_bt<float,2><<<g_fc2, 256, 0, stream>>>(
                hid, fc2_w + (size_t)L * C_ * FF_, fc2_b + (size_t)L * C_,
                nullptr, xres, T_, C_, FF_, FF_ / 2);
        }
    }
    ln_k<float><<<T_ / 4, 256, 0, stream>>>(xres, nf_g, nf_b, (float*)d_out);
}